// Round 1
// baseline (281.859 us; speedup 1.0000x reference)
//
#include <hip/hip_runtime.h>

static constexpr int BLOCK = 256;

// Per-sample loss contribution: 0.5*KL(t || softmax(l/T)) + 0.5*CE(l, label)
__device__ __forceinline__ float sample_contrib(float l0, float l1, float l2,
                                                float t0, float t1, float t2,
                                                float c, int lab) {
    // adaptive temperature (branch-free-ish; wave-divergence here is cheap)
    float temp;
    if (c > 0.9f)      temp = 1.5f;
    else if (c > 0.6f) temp = 2.0f;
    else               temp = fminf(2.5f + (0.6f - c) * 2.0f, 3.0f);
    float invT = 1.0f / temp;

    // log_softmax(logits / T)
    float a0 = l0 * invT, a1 = l1 * invT, a2 = l2 * invT;
    float m  = fmaxf(a0, fmaxf(a1, a2));
    float s  = __expf(a0 - m) + __expf(a1 - m) + __expf(a2 - m);
    float lse = __logf(s) + m;

    // KL(teacher || student_T) = sum t*(log t - logp);  t > 0 always here
    float kl = t0 * (__logf(t0) - (a0 - lse))
             + t1 * (__logf(t1) - (a1 - lse))
             + t2 * (__logf(t2) - (a2 - lse));

    // CE with unscaled logits
    float m2 = fmaxf(l0, fmaxf(l1, l2));
    float s2 = __expf(l0 - m2) + __expf(l1 - m2) + __expf(l2 - m2);
    float lse2 = __logf(s2) + m2;
    float ll = (lab == 0) ? l0 : ((lab == 1) ? l1 : l2);
    float ce = lse2 - ll;

    return 0.5f * kl + 0.5f * ce;
}

__global__ __launch_bounds__(BLOCK) void adl_main(
    const float* __restrict__ logits,
    const int*   __restrict__ hard,
    const float* __restrict__ soft,
    const float* __restrict__ conf,
    double*      __restrict__ ws_sum,
    int B4) // number of 4-sample groups
{
    int gid = blockIdx.x * BLOCK + threadIdx.x;
    double acc = 0.0;
    if (gid < B4) {
        const float4* l4 = (const float4*)logits;
        const float4* s4 = (const float4*)soft;
        const float4* c4 = (const float4*)conf;
        const int4*   h4 = (const int4*)hard;

        // 4 samples = 12 floats of logits / soft, 4 conf, 4 labels
        float4 la = l4[gid * 3 + 0];
        float4 lb = l4[gid * 3 + 1];
        float4 lc = l4[gid * 3 + 2];
        float4 sa = s4[gid * 3 + 0];
        float4 sb = s4[gid * 3 + 1];
        float4 sc = s4[gid * 3 + 2];
        float4 cf = c4[gid];
        int4   hh = h4[gid];

        float L[12] = {la.x, la.y, la.z, la.w, lb.x, lb.y, lb.z, lb.w,
                       lc.x, lc.y, lc.z, lc.w};
        float T[12] = {sa.x, sa.y, sa.z, sa.w, sb.x, sb.y, sb.z, sb.w,
                       sc.x, sc.y, sc.z, sc.w};
        float C[4]  = {cf.x, cf.y, cf.z, cf.w};
        int   H[4]  = {hh.x, hh.y, hh.z, hh.w};

        float part = 0.0f;
#pragma unroll
        for (int i = 0; i < 4; ++i) {
            part += sample_contrib(L[3 * i + 0], L[3 * i + 1], L[3 * i + 2],
                                   T[3 * i + 0], T[3 * i + 1], T[3 * i + 2],
                                   C[i], H[i]);
        }
        acc = (double)part;
    }

    // wave-64 shuffle reduction
#pragma unroll
    for (int off = 32; off > 0; off >>= 1)
        acc += __shfl_down(acc, off, 64);

    __shared__ double lds[BLOCK / 64];
    int lane = threadIdx.x & 63;
    int wid  = threadIdx.x >> 6;
    if (lane == 0) lds[wid] = acc;
    __syncthreads();
    if (threadIdx.x == 0) {
        double s = 0.0;
#pragma unroll
        for (int i = 0; i < BLOCK / 64; ++i) s += lds[i];
        atomicAdd(ws_sum, s); // one device-scope atomic per block
    }
}

__global__ void adl_finalize(const double* __restrict__ ws,
                             float* __restrict__ out, double invB) {
    out[0] = (float)(ws[0] * invB);
}

extern "C" void kernel_launch(void* const* d_in, const int* in_sizes, int n_in,
                              void* d_out, int out_size, void* d_ws, size_t ws_size,
                              hipStream_t stream) {
    const float* logits = (const float*)d_in[0];
    const int*   hard   = (const int*)d_in[1];
    const float* soft   = (const float*)d_in[2];
    const float* conf   = (const float*)d_in[3];

    int B  = in_sizes[1];   // hard_labels count = batch size
    int B4 = B / 4;         // B = 8388608 is divisible by 4

    double* ws = (double*)d_ws;
    hipMemsetAsync(ws, 0, sizeof(double), stream); // ws is re-poisoned每 call

    int grid = (B4 + BLOCK - 1) / BLOCK;
    adl_main<<<grid, BLOCK, 0, stream>>>(logits, hard, soft, conf, ws, B4);
    adl_finalize<<<1, 1, 0, stream>>>(ws, (float*)d_out, 1.0 / (double)B);
}

// Round 2
// 261.781 us; speedup vs baseline: 1.0767x; 1.0767x over previous
//
#include <hip/hip_runtime.h>

static constexpr int BLOCK = 256;
// 8 samples per thread: 6 float4 of logits + 6 float4 of soft + 2 float4 conf + 2 int4 labels

__device__ __forceinline__ float sample_contrib(float l0, float l1, float l2,
                                                float t0, float t1, float t2,
                                                float c, int lab) {
    // adaptive temperature
    float temp;
    if (c > 0.9f)      temp = 1.5f;
    else if (c > 0.6f) temp = 2.0f;
    else               temp = fminf(2.5f + (0.6f - c) * 2.0f, 3.0f);
    float invT = 1.0f / temp;

    // log_softmax(logits / T); note sum(t) == 1 so KL = sum t*log t - sum t*a + lse
    float a0 = l0 * invT, a1 = l1 * invT, a2 = l2 * invT;
    float m  = fmaxf(a0, fmaxf(a1, a2));
    float s  = __expf(a0 - m) + __expf(a1 - m) + __expf(a2 - m);
    float lse = __logf(s) + m;

    float tlogt = t0 * __logf(t0) + t1 * __logf(t1) + t2 * __logf(t2);
    float ta    = t0 * a0 + t1 * a1 + t2 * a2;
    float kl    = tlogt - ta + lse;

    // CE with unscaled logits
    float m2 = fmaxf(l0, fmaxf(l1, l2));
    float s2 = __expf(l0 - m2) + __expf(l1 - m2) + __expf(l2 - m2);
    float lse2 = __logf(s2) + m2;
    float ll = (lab == 0) ? l0 : ((lab == 1) ? l1 : l2);
    float ce = lse2 - ll;

    return 0.5f * kl + 0.5f * ce;
}

__global__ __launch_bounds__(BLOCK) void adl_main(
    const float4* __restrict__ l4,
    const int4*   __restrict__ h4,
    const float4* __restrict__ s4,
    const float4* __restrict__ c4,
    double*       __restrict__ ws_sum,
    int nGroups) // number of 8-sample groups
{
    int gid = blockIdx.x * BLOCK + threadIdx.x;
    float part = 0.0f;
    if (gid < nGroups) {
        float4 L[6], S[6], C2[2];
        int4   H2[2];
#pragma unroll
        for (int i = 0; i < 6; ++i) L[i] = l4[gid * 6 + i];
#pragma unroll
        for (int i = 0; i < 6; ++i) S[i] = s4[gid * 6 + i];
#pragma unroll
        for (int i = 0; i < 2; ++i) C2[i] = c4[gid * 2 + i];
#pragma unroll
        for (int i = 0; i < 2; ++i) H2[i] = h4[gid * 2 + i];
        // Pin: all 16 global loads issue before any compute (max loads in flight).
        __builtin_amdgcn_sched_barrier(0);

        const float* Lf = (const float*)L;
        const float* Sf = (const float*)S;
        const float* Cf = (const float*)C2;
        const int*   Hf = (const int*)H2;
#pragma unroll
        for (int i = 0; i < 8; ++i) {
            part += sample_contrib(Lf[3 * i + 0], Lf[3 * i + 1], Lf[3 * i + 2],
                                   Sf[3 * i + 0], Sf[3 * i + 1], Sf[3 * i + 2],
                                   Cf[i], Hf[i]);
        }
    }

    double acc = (double)part;
#pragma unroll
    for (int off = 32; off > 0; off >>= 1)
        acc += __shfl_down(acc, off, 64);

    __shared__ double lds[BLOCK / 64];
    int lane = threadIdx.x & 63;
    int wid  = threadIdx.x >> 6;
    if (lane == 0) lds[wid] = acc;
    __syncthreads();
    if (threadIdx.x == 0) {
        double s = 0.0;
#pragma unroll
        for (int i = 0; i < BLOCK / 64; ++i) s += lds[i];
        atomicAdd(ws_sum, s);
    }
}

__global__ void adl_finalize(const double* __restrict__ ws,
                             float* __restrict__ out, double invB) {
    out[0] = (float)(ws[0] * invB);
}

extern "C" void kernel_launch(void* const* d_in, const int* in_sizes, int n_in,
                              void* d_out, int out_size, void* d_ws, size_t ws_size,
                              hipStream_t stream) {
    const float* logits = (const float*)d_in[0];
    const int*   hard   = (const int*)d_in[1];
    const float* soft   = (const float*)d_in[2];
    const float* conf   = (const float*)d_in[3];

    int B  = in_sizes[1];   // batch size (hard_labels count)
    int nG = B / 8;         // 8388608 / 8 = 1048576 groups

    double* ws = (double*)d_ws;
    hipMemsetAsync(ws, 0, sizeof(double), stream);

    int grid = (nG + BLOCK - 1) / BLOCK;
    adl_main<<<grid, BLOCK, 0, stream>>>((const float4*)logits, (const int4*)hard,
                                         (const float4*)soft, (const float4*)conf,
                                         ws, nG);
    adl_finalize<<<1, 1, 0, stream>>>(ws, (float*)d_out, 1.0 / (double)B);
}